// Round 1
// baseline (300.070 us; speedup 1.0000x reference)
//
#include <hip/hip_runtime.h>

// Problem constants (fixed by setup_inputs: H=W=4096, offset=16)
constexpr int W = 4096;
constexpr int H = 4096;
constexpr int HW = W * H;
constexpr int OFFSET = 16;

constexpr int TX = 64;  // tile width  (threads x)
constexpr int TY = 4;   // tile height (threads y)
constexpr int TILES_X = W / TX;          // 64
constexpr int TILES_Y = H / TY;          // 1024
constexpr int NTILES = TILES_X * TILES_Y; // 65536

__device__ __forceinline__ float clamp01(float v) {
    return fminf(fmaxf(v, 0.0f), 1.0f);
}

// Fill one pixel at ring t (t >= 2): average of 3x3 neighbors with d == t-1.
// Read set (d==t-1, stable) and write set (d==t) are disjoint -> race-free.
__device__ __forceinline__ void fill_pixel(float* __restrict__ out,
                                           const unsigned char* __restrict__ dmap,
                                           int x, int y, int t) {
    float s0 = 0.f, s1 = 0.f, s2 = 0.f;
    int cnt = 0;
    #pragma unroll
    for (int dy = -1; dy <= 1; ++dy) {
        int ny = y + dy;
        if (ny < 0 || ny >= H) continue;
        #pragma unroll
        for (int dx = -1; dx <= 1; ++dx) {
            int nx = x + dx;
            if (nx < 0 || nx >= W) continue;
            int q = ny * W + nx;
            if (dmap[q] == (unsigned char)(t - 1)) {
                cnt++;
                s0 += out[q];
                s1 += out[HW + q];
                s2 += out[2 * HW + q];
            }
        }
    }
    float inv = 1.0f / ((float)cnt + 1e-7f);
    int p = y * W + x;
    out[p]          = clamp01(s0 * inv);
    out[HW + p]     = clamp01(s1 * inv);
    out[2 * HW + p] = clamp01(s2 * inv);
}

// Pass 1: compute mask, distance classification, write d<=1 final values,
// zeros elsewhere, u8 d-map, and per-tile max-d table.
__global__ __launch_bounds__(TX * TY) void pass1_kernel(
    const float* __restrict__ rgb, const float* __restrict__ alpha,
    float* __restrict__ out, unsigned char* __restrict__ dmap,
    unsigned char* __restrict__ tbl)
{
    __shared__ unsigned char sm[TY + 4][TX + 8];  // mask tile with halo 2 (padded)
    __shared__ unsigned int tmax;

    const int tx = threadIdx.x, ty = threadIdx.y;
    const int tid = ty * TX + tx;
    if (tid == 0) tmax = 0;

    const int x0 = blockIdx.x * TX, y0 = blockIdx.y * TY;

    // cooperative mask load: rows [y0-2, y0+TY+1], cols [x0-2, x0+TX+1]
    for (int i = tid; i < (TY + 4) * (TX + 4); i += TX * TY) {
        int row = i / (TX + 4);
        int col = i - row * (TX + 4);
        int gy = y0 - 2 + row;
        int gx = x0 - 2 + col;
        unsigned char v = 0;
        if (gx >= 0 && gx < W && gy >= 0 && gy < H)
            v = (alpha[gy * W + gx] > 0.0f) ? 1 : 0;
        sm[row][col] = v;
    }
    __syncthreads();

    const int x = x0 + tx, y = y0 + ty;
    const int lx = tx + 2, ly = ty + 2;
    const int p = y * W + x;

    unsigned int d;
    float o0, o1, o2;

    if (sm[ly][lx]) {
        d = 0;
        o0 = rgb[p];
        o1 = rgb[HW + p];
        o2 = rgb[2 * HW + p];
    } else {
        int cnt9 = 0;
        #pragma unroll
        for (int dy = -1; dy <= 1; ++dy)
            #pragma unroll
            for (int dx = -1; dx <= 1; ++dx)
                cnt9 += sm[ly + dy][lx + dx];
        if (cnt9 > 0) {
            d = 1;
            float s0 = 0.f, s1 = 0.f, s2 = 0.f;
            #pragma unroll
            for (int dy = -1; dy <= 1; ++dy)
                #pragma unroll
                for (int dx = -1; dx <= 1; ++dx)
                    if (sm[ly + dy][lx + dx]) {
                        int q = (y + dy) * W + (x + dx);
                        s0 += rgb[q];
                        s1 += rgb[HW + q];
                        s2 += rgb[2 * HW + q];
                    }
            float inv = 1.0f / ((float)cnt9 + 1e-7f);
            o0 = s0 * inv; o1 = s1 * inv; o2 = s2 * inv;
        } else {
            o0 = o1 = o2 = 0.f;
            // 5x5 outer ring via LDS halo
            int any2 = 0;
            #pragma unroll
            for (int dx = -2; dx <= 2; ++dx)
                any2 += sm[ly - 2][lx + dx] + sm[ly + 2][lx + dx];
            #pragma unroll
            for (int dy = -1; dy <= 1; ++dy)
                any2 += sm[ly + dy][lx - 2] + sm[ly + dy][lx + 2];
            if (any2) {
                d = 2;
            } else {
                // rare (P ~ 2^-25 per pixel): expanding Chebyshev ring scan
                d = 255;
                for (int r = 3; r <= OFFSET; ++r) {
                    bool f = false;
                    for (int dx = -r; dx <= r && !f; ++dx) {
                        int gx = x + dx;
                        if (gx < 0 || gx >= W) continue;
                        int gy = y - r;
                        if (gy >= 0 && alpha[gy * W + gx] > 0.0f) f = true;
                        gy = y + r;
                        if (!f && gy < H && alpha[gy * W + gx] > 0.0f) f = true;
                    }
                    for (int dy = -r + 1; dy <= r - 1 && !f; ++dy) {
                        int gy = y + dy;
                        if (gy < 0 || gy >= H) continue;
                        int gx = x - r;
                        if (gx >= 0 && alpha[gy * W + gx] > 0.0f) f = true;
                        gx = x + r;
                        if (!f && gx < W && alpha[gy * W + gx] > 0.0f) f = true;
                    }
                    if (f) { d = r; break; }
                }
            }
        }
    }

    out[p]          = clamp01(o0);
    out[HW + p]     = clamp01(o1);
    out[2 * HW + p] = clamp01(o2);
    dmap[p] = (unsigned char)d;

    if (d >= 2 && d != 255) atomicMax(&tmax, d);
    __syncthreads();
    if (tid == 0)
        tbl[blockIdx.y * gridDim.x + blockIdx.x] = (unsigned char)(tmax > 255u ? 255u : tmax);
}

// Dense tail pass (used for t=2 where ~40% of tiles have work).
__global__ __launch_bounds__(TX * TY) void tail_dense(
    float* __restrict__ out, const unsigned char* __restrict__ dmap,
    const unsigned char* __restrict__ tbl, int t)
{
    __shared__ unsigned int go;
    if (threadIdx.x == 0 && threadIdx.y == 0)
        go = tbl[blockIdx.y * gridDim.x + blockIdx.x];
    __syncthreads();
    if (go < (unsigned int)t) return;

    int x = blockIdx.x * TX + threadIdx.x;
    int y = blockIdx.y * TY + threadIdx.y;
    int p = y * W + x;
    if (dmap[p] != (unsigned char)t) return;
    fill_pixel(out, dmap, x, y, t);
}

// Sparse tail pass (t>=3: expected ~0-2 active tiles in the whole image).
// One thread per 64x4 tile; active threads scan their tile serially.
__global__ __launch_bounds__(256) void tail_sparse(
    float* __restrict__ out, const unsigned char* __restrict__ dmap,
    const unsigned char* __restrict__ tbl, int t)
{
    int tile = blockIdx.x * blockDim.x + threadIdx.x;
    if (tile >= NTILES) return;
    if (tbl[tile] < (unsigned char)t) return;

    int bx = tile % TILES_X;
    int by = tile / TILES_X;
    int x0 = bx * TX, y0 = by * TY;
    for (int yy = 0; yy < TY; ++yy) {
        int y = y0 + yy;
        const unsigned char* drow = dmap + y * W;
        for (int xx = 0; xx < TX; ++xx) {
            int x = x0 + xx;
            if (drow[x] == (unsigned char)t)
                fill_pixel(out, dmap, x, y, t);
        }
    }
}

extern "C" void kernel_launch(void* const* d_in, const int* in_sizes, int n_in,
                              void* d_out, int out_size, void* d_ws, size_t ws_size,
                              hipStream_t stream) {
    const float* rgb   = (const float*)d_in[0];
    const float* alpha = (const float*)d_in[1];
    float* out = (float*)d_out;

    unsigned char* dmap = (unsigned char*)d_ws;        // HW bytes
    unsigned char* tbl  = dmap + (size_t)HW;           // NTILES bytes

    dim3 grid(TILES_X, TILES_Y);
    dim3 block(TX, TY);

    pass1_kernel<<<grid, block, 0, stream>>>(rgb, alpha, out, dmap, tbl);
    tail_dense<<<grid, block, 0, stream>>>(out, dmap, tbl, 2);
    for (int t = 3; t <= OFFSET; ++t)
        tail_sparse<<<256, 256, 0, stream>>>(out, dmap, tbl, t);
}

// Round 2
// 170.342 us; speedup vs baseline: 1.7616x; 1.7616x over previous
//
#include <hip/hip_runtime.h>

// Problem constants (fixed by setup_inputs: H=W=4096, offset=16)
constexpr int W = 4096;
constexpr int H = 4096;
constexpr int HW = W * H;

constexpr int BX = 32, BY = 8;            // 256 threads
constexpr int TILE_W = BX * 4;            // 128 px wide (4 px / thread)
constexpr int GRID_X = W / TILE_W;        // 32
constexpr int GRID_Y = H / BY;            // 512

typedef unsigned char u8;
typedef unsigned int u32;

__device__ __forceinline__ float clamp01(float v) { return fminf(fmaxf(v, 0.f), 1.f); }
__device__ __forceinline__ float4 ld4(const float* p) { return *reinterpret_cast<const float4*>(p); }
__device__ __forceinline__ void st4(float* p, float4 v) { *reinterpret_cast<float4*>(p) = v; }
__device__ __forceinline__ float4 z4() { return make_float4(0.f, 0.f, 0.f, 0.f); }
__device__ __forceinline__ float rcp_f(float x) { return __builtin_amdgcn_rcpf(x); }

// Rare-path distance classification: no mask in 3x3 -> check 5x5 ring, then
// expanding Chebyshev rings r=3..16.  ~0.2% of pixels reach the 5x5 check,
// ~1e-7 of pixels reach the ring scan.
__device__ __attribute__((noinline)) u32 far_distance(
    const float* __restrict__ alpha, int x, int y)
{
    for (int dy = -2; dy <= 2; ++dy) {
        int yy = y + dy;
        if (yy < 0 || yy >= H) continue;
        if (dy == -2 || dy == 2) {
            for (int dx = -2; dx <= 2; ++dx) {
                int xx = x + dx;
                if (xx < 0 || xx >= W) continue;
                if (alpha[yy * W + xx] > 0.f) return 2;
            }
        } else {
            if (x - 2 >= 0 && alpha[yy * W + x - 2] > 0.f) return 2;
            if (x + 2 < W && alpha[yy * W + x + 2] > 0.f) return 2;
        }
    }
    for (int r = 3; r <= 16; ++r) {
        bool f = false;
        for (int dx = -r; dx <= r && !f; ++dx) {
            int gx = x + dx;
            if (gx < 0 || gx >= W) continue;
            int gy = y - r;
            if (gy >= 0 && alpha[gy * W + gx] > 0.f) f = true;
            gy = y + r;
            if (!f && gy < H && alpha[gy * W + gx] > 0.f) f = true;
        }
        for (int dy = -r + 1; dy <= r - 1 && !f; ++dy) {
            int gy = y + dy;
            if (gy < 0 || gy >= H) continue;
            int gx = x - r;
            if (gx >= 0 && alpha[gy * W + gx] > 0.f) f = true;
            gx = x + r;
            if (!f && gx < W && alpha[gy * W + gx] > 0.f) f = true;
        }
        if (f) return r;
    }
    return 255;
}

__device__ __forceinline__ float4 plane_vsum(const float* __restrict__ base, int p0,
                                             bool up, bool dn,
                                             float4 mU, float4 mC, float4 mD,
                                             float4* center)
{
    float4 u = up ? ld4(base + p0 - W) : z4();
    float4 c = ld4(base + p0);
    float4 d = dn ? ld4(base + p0 + W) : z4();
    *center = c;
    float4 r;
    r.x = u.x * mU.x + c.x * mC.x + d.x * mD.x;
    r.y = u.y * mU.y + c.y * mC.y + d.y * mD.y;
    r.z = u.z * mU.z + c.z * mC.z + d.z * mD.z;
    r.w = u.w * mU.w + c.w * mC.w + d.w * mD.w;
    return r;
}

// Pass 1: separable 3x3 box-sums of (mask, masked rgb); write final values for
// d<=1, zeros elsewhere, u8 d-map, and compact the d>=3 pixels into a list.
__global__ __launch_bounds__(BX * BY) void pass1_kernel(
    const float* __restrict__ rgb, const float* __restrict__ alpha,
    float* __restrict__ out, u8* __restrict__ dmap,
    u32* __restrict__ cnt, int* __restrict__ list, u32 cap)
{
    // vertical-sum planes: r,g,b,wt.  cols 0..127 normal; 128 = right halo,
    // 130 = left halo (keeps the float4 region 16B-aligned).
    __shared__ __align__(16) float vs[4][BY][132];

    const int tx = threadIdx.x, ty = threadIdx.y;
    const int x0 = blockIdx.x * TILE_W + tx * 4;
    const int y  = blockIdx.y * BY + ty;
    const int p0 = y * W + x0;

    const bool up = (y > 0), dn = (y < H - 1);

    float4 aU = up ? ld4(alpha + p0 - W) : z4();
    float4 aC = ld4(alpha + p0);
    float4 aD = dn ? ld4(alpha + p0 + W) : z4();

    float4 mU = make_float4(aU.x > 0.f, aU.y > 0.f, aU.z > 0.f, aU.w > 0.f);
    float4 mC = make_float4(aC.x > 0.f, aC.y > 0.f, aC.z > 0.f, aC.w > 0.f);
    float4 mD = make_float4(aD.x > 0.f, aD.y > 0.f, aD.z > 0.f, aD.w > 0.f);

    float4 vwt;
    vwt.x = mU.x + mC.x + mD.x;
    vwt.y = mU.y + mC.y + mD.y;
    vwt.z = mU.z + mC.z + mD.z;
    vwt.w = mU.w + mC.w + mD.w;

    const float* Gp = rgb + HW;
    const float* Bp = rgb + 2 * HW;

    float4 rC, gC, bC;
    float4 vr = plane_vsum(rgb, p0, up, dn, mU, mC, mD, &rC);
    float4 vg = plane_vsum(Gp,  p0, up, dn, mU, mC, mD, &gC);
    float4 vb = plane_vsum(Bp,  p0, up, dn, mU, mC, mD, &bC);

    st4(&vs[0][ty][tx * 4], vr);
    st4(&vs[1][ty][tx * 4], vg);
    st4(&vs[2][ty][tx * 4], vb);
    st4(&vs[3][ty][tx * 4], vwt);

    // block-edge halo columns (x0-1 / x0+4), computed scalar by edge threads
    if (tx == 0 || tx == BX - 1) {
        int xh   = (tx == 0) ? x0 - 1 : x0 + 4;
        int slot = (tx == 0) ? 130 : 128;
        float sr = 0.f, sg = 0.f, sb = 0.f, sw = 0.f;
        if (xh >= 0 && xh < W) {
            #pragma unroll
            for (int dy = -1; dy <= 1; ++dy) {
                int yy = y + dy;
                if (yy < 0 || yy >= H) continue;
                int q = yy * W + xh;
                float m = (alpha[q] > 0.f) ? 1.f : 0.f;
                sw += m;
                sr += m * rgb[q];
                sg += m * Gp[q];
                sb += m * Bp[q];
            }
        }
        vs[0][ty][slot] = sr;
        vs[1][ty][slot] = sg;
        vs[2][ty][slot] = sb;
        vs[3][ty][slot] = sw;
    }
    __syncthreads();

    const int cL = (tx == 0) ? 130 : tx * 4 - 1;
    const int cR = (tx == BX - 1) ? 128 : tx * 4 + 4;

    float sr[4], sg[4], sb[4], sw[4];
    {
        float4 v = ld4(&vs[0][ty][tx * 4]);
        float l = vs[0][ty][cL], r = vs[0][ty][cR];
        sr[0] = l + v.x + v.y; sr[1] = v.x + v.y + v.z;
        sr[2] = v.y + v.z + v.w; sr[3] = v.z + v.w + r;
    }
    {
        float4 v = ld4(&vs[1][ty][tx * 4]);
        float l = vs[1][ty][cL], r = vs[1][ty][cR];
        sg[0] = l + v.x + v.y; sg[1] = v.x + v.y + v.z;
        sg[2] = v.y + v.z + v.w; sg[3] = v.z + v.w + r;
    }
    {
        float4 v = ld4(&vs[2][ty][tx * 4]);
        float l = vs[2][ty][cL], r = vs[2][ty][cR];
        sb[0] = l + v.x + v.y; sb[1] = v.x + v.y + v.z;
        sb[2] = v.y + v.z + v.w; sb[3] = v.z + v.w + r;
    }
    {
        float4 v = ld4(&vs[3][ty][tx * 4]);
        float l = vs[3][ty][cL], r = vs[3][ty][cR];
        sw[0] = l + v.x + v.y; sw[1] = v.x + v.y + v.z;
        sw[2] = v.y + v.z + v.w; sw[3] = v.z + v.w + r;
    }

    const float mca[4] = {mC.x, mC.y, mC.z, mC.w};
    const float rca[4] = {rC.x, rC.y, rC.z, rC.w};
    const float gca[4] = {gC.x, gC.y, gC.z, gC.w};
    const float bca[4] = {bC.x, bC.y, bC.z, bC.w};

    float o_r[4], o_g[4], o_b[4];
    u32 dv[4];

    #pragma unroll
    for (int i = 0; i < 4; ++i) {
        if (mca[i] > 0.f) {
            dv[i] = 0;
            o_r[i] = rca[i]; o_g[i] = gca[i]; o_b[i] = bca[i];
        } else if (sw[i] > 0.f) {
            dv[i] = 1;
            float inv = rcp_f(sw[i] + 1e-7f);
            o_r[i] = sr[i] * inv; o_g[i] = sg[i] * inv; o_b[i] = sb[i] * inv;
        } else {
            u32 d = far_distance(alpha, x0 + i, y);
            dv[i] = d;
            o_r[i] = 0.f; o_g[i] = 0.f; o_b[i] = 0.f;
            if (d >= 3 && d <= 16) {
                u32 idx = atomicAdd(cnt, 1u);
                if (idx < cap) list[idx] = p0 + i;
            }
        }
    }

    st4(out + p0, make_float4(clamp01(o_r[0]), clamp01(o_r[1]),
                              clamp01(o_r[2]), clamp01(o_r[3])));
    st4(out + HW + p0, make_float4(clamp01(o_g[0]), clamp01(o_g[1]),
                                   clamp01(o_g[2]), clamp01(o_g[3])));
    st4(out + 2 * HW + p0, make_float4(clamp01(o_b[0]), clamp01(o_b[1]),
                                       clamp01(o_b[2]), clamp01(o_b[3])));
    *reinterpret_cast<uchar4*>(dmap + p0) =
        make_uchar4((u8)dv[0], (u8)dv[1], (u8)dv[2], (u8)dv[3]);
}

// Fill one pixel at ring t (t >= 2): average of 3x3 neighbors with d == t-1.
// (For a d==t pixel, every neighbor has d >= t-1, so "filled" == "d == t-1".)
__device__ __forceinline__ void fill_pixel(float* __restrict__ out,
                                           const u8* __restrict__ dmap,
                                           int x, int y, int t)
{
    float s0 = 0.f, s1 = 0.f, s2 = 0.f;
    int cnt = 0;
    #pragma unroll
    for (int dy = -1; dy <= 1; ++dy) {
        int ny = y + dy;
        if (ny < 0 || ny >= H) continue;
        #pragma unroll
        for (int dx = -1; dx <= 1; ++dx) {
            int nx = x + dx;
            if (nx < 0 || nx >= W) continue;
            int q = ny * W + nx;
            if (dmap[q] == (u8)(t - 1)) {
                cnt++;
                s0 += out[q];
                s1 += out[HW + q];
                s2 += out[2 * HW + q];
            }
        }
    }
    float inv = rcp_f((float)cnt + 1e-7f);
    int p = y * W + x;
    out[p]          = clamp01(s0 * inv);
    out[HW + p]     = clamp01(s1 * inv);
    out[2 * HW + p] = clamp01(s2 * inv);
}

// t=2 pass: one thread per 4 px, self-gated on a uchar4 dmap read.
__global__ __launch_bounds__(256) void tail_dense(
    float* __restrict__ out, const u8* __restrict__ dmap)
{
    int idx = blockIdx.x * 256 + threadIdx.x;
    int p = idx * 4;
    uchar4 dq = *reinterpret_cast<const uchar4*>(dmap + p);
    if (dq.x != 2 && dq.y != 2 && dq.z != 2 && dq.w != 2) return;
    int y = p >> 12;            // p / W
    int xb = p & (W - 1);
    if (dq.x == 2) fill_pixel(out, dmap, xb + 0, y, 2);
    if (dq.y == 2) fill_pixel(out, dmap, xb + 1, y, 2);
    if (dq.z == 2) fill_pixel(out, dmap, xb + 2, y, 2);
    if (dq.w == 2) fill_pixel(out, dmap, xb + 3, y, 2);
}

// t=3..16 in ONE single-block kernel over the compacted d>=3 list
// (expected ~0-2 entries).  __syncthreads between rings gives ordering;
// intra-block global writes are visible after the barrier.
__global__ __launch_bounds__(256) void tail_far(
    float* __restrict__ out, const u8* __restrict__ dmap,
    const int* __restrict__ list, const u32* __restrict__ cnt, u32 cap)
{
    u32 n = *cnt;
    if (n > cap) n = cap;
    for (int t = 3; t <= 16; ++t) {
        for (u32 i = threadIdx.x; i < n; i += 256) {
            int p = list[i];
            if (dmap[p] == (u8)t)
                fill_pixel(out, dmap, p & (W - 1), p >> 12, t);
        }
        __syncthreads();
    }
}

extern "C" void kernel_launch(void* const* d_in, const int* in_sizes, int n_in,
                              void* d_out, int out_size, void* d_ws, size_t ws_size,
                              hipStream_t stream) {
    const float* rgb   = (const float*)d_in[0];
    const float* alpha = (const float*)d_in[1];
    float* out = (float*)d_out;

    u8* dmap  = (u8*)d_ws;                           // HW bytes
    u32* cnt  = (u32*)((char*)d_ws + HW);            // 4 bytes (16B slot)
    int* list = (int*)((char*)d_ws + HW + 16);
    u32 cap = 0;
    if (ws_size > (size_t)HW + 16) {
        size_t c = (ws_size - HW - 16) / 4;
        cap = (u32)(c > (1u << 22) ? (1u << 22) : c);
    }

    hipMemsetAsync(cnt, 0, 4, stream);

    pass1_kernel<<<dim3(GRID_X, GRID_Y), dim3(BX, BY), 0, stream>>>(
        rgb, alpha, out, dmap, cnt, list, cap);
    tail_dense<<<HW / 4 / 256, 256, 0, stream>>>(out, dmap);
    tail_far<<<1, 256, 0, stream>>>(out, dmap, list, cnt, cap);
}

// Round 3
// 158.320 us; speedup vs baseline: 1.8953x; 1.0759x over previous
//
#include <hip/hip_runtime.h>

// Problem constants (fixed by setup_inputs: H=W=4096, offset=16)
constexpr int W = 4096;
constexpr int H = 4096;
constexpr int HW = W * H;

constexpr int BX = 64, BY = 4;            // 256 threads; wave = one 256-px row
constexpr int TILE_W = BX * 4;            // 256 px
constexpr int GRID_X = W / TILE_W;        // 16
constexpr int GRID_Y = H / BY;            // 1024

typedef unsigned char u8;
typedef unsigned int u32;

__device__ __forceinline__ float clamp01(float v) { return fminf(fmaxf(v, 0.f), 1.f); }
__device__ __forceinline__ float4 ld4(const float* p) { return *reinterpret_cast<const float4*>(p); }
__device__ __forceinline__ void st4(float* p, float4 v) { *reinterpret_cast<float4*>(p) = v; }
__device__ __forceinline__ float4 z4() { return make_float4(0.f, 0.f, 0.f, 0.f); }
__device__ __forceinline__ float rcp_f(float x) { return __builtin_amdgcn_rcpf(x); }

// Rare-path distance classification (~0.1% of pixels): 5x5 ring, then
// expanding Chebyshev rings r=3..16 (~1e-7 of pixels).
__device__ __attribute__((noinline)) u32 far_distance(
    const float* __restrict__ alpha, int x, int y)
{
    for (int dy = -2; dy <= 2; ++dy) {
        int yy = y + dy;
        if (yy < 0 || yy >= H) continue;
        if (dy == -2 || dy == 2) {
            for (int dx = -2; dx <= 2; ++dx) {
                int xx = x + dx;
                if (xx < 0 || xx >= W) continue;
                if (alpha[yy * W + xx] > 0.f) return 2;
            }
        } else {
            if (x - 2 >= 0 && alpha[yy * W + x - 2] > 0.f) return 2;
            if (x + 2 < W && alpha[yy * W + x + 2] > 0.f) return 2;
        }
    }
    for (int r = 3; r <= 16; ++r) {
        bool f = false;
        for (int dx = -r; dx <= r && !f; ++dx) {
            int gx = x + dx;
            if (gx < 0 || gx >= W) continue;
            int gy = y - r;
            if (gy >= 0 && alpha[gy * W + gx] > 0.f) f = true;
            gy = y + r;
            if (!f && gy < H && alpha[gy * W + gx] > 0.f) f = true;
        }
        for (int dy = -r + 1; dy <= r - 1 && !f; ++dy) {
            int gy = y + dy;
            if (gy < 0 || gy >= H) continue;
            int gx = x - r;
            if (gx >= 0 && alpha[gy * W + gx] > 0.f) f = true;
            gx = x + r;
            if (!f && gx < W && alpha[gy * W + gx] > 0.f) f = true;
        }
        if (f) return r;
    }
    return 255;
}

__device__ __forceinline__ float4 vsum4(float4 u, float4 c, float4 d,
                                        float4 mU, float4 mC, float4 mD)
{
    float4 r;
    r.x = u.x * mU.x + c.x * mC.x + d.x * mD.x;
    r.y = u.y * mU.y + c.y * mC.y + d.y * mD.y;
    r.z = u.z * mU.z + c.z * mC.z + d.z * mD.z;
    r.w = u.w * mU.w + c.w * mC.w + d.w * mD.w;
    return r;
}

// Pass 1: streaming separable 3x3 box-sums; no LDS, no barrier.
// Horizontal halo columns come from neighbor lanes via shuffle; lanes 0/63
// compute the tile-edge halo vertical sums from global directly.
__global__ __launch_bounds__(BX * BY) void pass1_kernel(
    const float* __restrict__ rgb, const float* __restrict__ alpha,
    float* __restrict__ out, u8* __restrict__ dmap,
    u32* __restrict__ cnt, int* __restrict__ list, u32 cap)
{
    const int tx = threadIdx.x;               // 0..63 (one wave per row)
    const int ty = threadIdx.y;               // 0..3
    const int x0 = blockIdx.x * TILE_W + tx * 4;
    const int y  = blockIdx.y * BY + ty;
    const int p0 = y * W + x0;
    const bool up = (y > 0), dn = (y < H - 1);

    const float* Gp = rgb + HW;
    const float* Bp = rgb + 2 * HW;

    // ---- issue all 12 row loads up front (max memory-level parallelism) ----
    float4 aU = up ? ld4(alpha + p0 - W) : z4();
    float4 aC = ld4(alpha + p0);
    float4 aD = dn ? ld4(alpha + p0 + W) : z4();
    float4 rU = up ? ld4(rgb + p0 - W) : z4();
    float4 rC = ld4(rgb + p0);
    float4 rD = dn ? ld4(rgb + p0 + W) : z4();
    float4 gU = up ? ld4(Gp + p0 - W) : z4();
    float4 gC = ld4(Gp + p0);
    float4 gD = dn ? ld4(Gp + p0 + W) : z4();
    float4 bU = up ? ld4(Bp + p0 - W) : z4();
    float4 bC = ld4(Bp + p0);
    float4 bD = dn ? ld4(Bp + p0 + W) : z4();

    float4 mU = make_float4(aU.x > 0.f, aU.y > 0.f, aU.z > 0.f, aU.w > 0.f);
    float4 mC = make_float4(aC.x > 0.f, aC.y > 0.f, aC.z > 0.f, aC.w > 0.f);
    float4 mD = make_float4(aD.x > 0.f, aD.y > 0.f, aD.z > 0.f, aD.w > 0.f);

    float4 vw;
    vw.x = mU.x + mC.x + mD.x;
    vw.y = mU.y + mC.y + mD.y;
    vw.z = mU.z + mC.z + mD.z;
    vw.w = mU.w + mC.w + mD.w;
    float4 vr = vsum4(rU, rC, rD, mU, mC, mD);
    float4 vg = vsum4(gU, gC, gD, mU, mC, mD);
    float4 vb = vsum4(bU, bC, bD, mU, mC, mD);

    // ---- horizontal halo: neighbor lane's edge vertical sums ----
    float lw = __shfl_up(vw.w, 1), rw = __shfl_down(vw.x, 1);
    float lr = __shfl_up(vr.w, 1), rr = __shfl_down(vr.x, 1);
    float lg = __shfl_up(vg.w, 1), rg = __shfl_down(vg.x, 1);
    float lb = __shfl_up(vb.w, 1), rb = __shfl_down(vb.x, 1);

    // tile-edge halo columns: lanes 0 / 63 compute from global (predicated)
    if (tx == 0 || tx == BX - 1) {
        int xh = (tx == 0) ? x0 - 1 : x0 + 4;
        float hr = 0.f, hg = 0.f, hb = 0.f, hw = 0.f;
        if (xh >= 0 && xh < W) {
            #pragma unroll
            for (int dy = -1; dy <= 1; ++dy) {
                int yy = y + dy;
                if (yy < 0 || yy >= H) continue;
                int q = yy * W + xh;
                float m = (alpha[q] > 0.f) ? 1.f : 0.f;
                hw += m;
                hr += m * rgb[q];
                hg += m * Gp[q];
                hb += m * Bp[q];
            }
        }
        if (tx == 0) { lw = hw; lr = hr; lg = hg; lb = hb; }
        else         { rw = hw; rr = hr; rg = hg; rb = hb; }
    }

    float sw[4] = { lw + vw.x + vw.y, vw.x + vw.y + vw.z,
                    vw.y + vw.z + vw.w, vw.z + vw.w + rw };
    float sr[4] = { lr + vr.x + vr.y, vr.x + vr.y + vr.z,
                    vr.y + vr.z + vr.w, vr.z + vr.w + rr };
    float sg[4] = { lg + vg.x + vg.y, vg.x + vg.y + vg.z,
                    vg.y + vg.z + vg.w, vg.z + vg.w + rg };
    float sb[4] = { lb + vb.x + vb.y, vb.x + vb.y + vb.z,
                    vb.y + vb.z + vb.w, vb.z + vb.w + rb };

    const float mca[4] = {mC.x, mC.y, mC.z, mC.w};
    const float rca[4] = {rC.x, rC.y, rC.z, rC.w};
    const float gca[4] = {gC.x, gC.y, gC.z, gC.w};
    const float bca[4] = {bC.x, bC.y, bC.z, bC.w};

    float o_r[4], o_g[4], o_b[4];
    u32 dv[4];

    #pragma unroll
    for (int i = 0; i < 4; ++i) {
        if (mca[i] > 0.f) {
            dv[i] = 0;
            o_r[i] = rca[i]; o_g[i] = gca[i]; o_b[i] = bca[i];
        } else if (sw[i] > 0.f) {
            dv[i] = 1;
            float inv = rcp_f(sw[i] + 1e-7f);
            o_r[i] = sr[i] * inv; o_g[i] = sg[i] * inv; o_b[i] = sb[i] * inv;
        } else {
            u32 d = far_distance(alpha, x0 + i, y);
            dv[i] = d;
            o_r[i] = 0.f; o_g[i] = 0.f; o_b[i] = 0.f;
            if (d >= 3 && d <= 16) {
                u32 idx = atomicAdd(cnt, 1u);
                if (idx < cap) list[idx] = p0 + i;
            }
        }
    }

    st4(out + p0, make_float4(clamp01(o_r[0]), clamp01(o_r[1]),
                              clamp01(o_r[2]), clamp01(o_r[3])));
    st4(out + HW + p0, make_float4(clamp01(o_g[0]), clamp01(o_g[1]),
                                   clamp01(o_g[2]), clamp01(o_g[3])));
    st4(out + 2 * HW + p0, make_float4(clamp01(o_b[0]), clamp01(o_b[1]),
                                       clamp01(o_b[2]), clamp01(o_b[3])));
    *reinterpret_cast<uchar4*>(dmap + p0) =
        make_uchar4((u8)dv[0], (u8)dv[1], (u8)dv[2], (u8)dv[3]);
}

// Fill one pixel at ring t (t >= 2): average of 3x3 neighbors with d == t-1.
__device__ __forceinline__ void fill_pixel(float* __restrict__ out,
                                           const u8* __restrict__ dmap,
                                           int x, int y, int t)
{
    float s0 = 0.f, s1 = 0.f, s2 = 0.f;
    int cnt = 0;
    #pragma unroll
    for (int dy = -1; dy <= 1; ++dy) {
        int ny = y + dy;
        if (ny < 0 || ny >= H) continue;
        #pragma unroll
        for (int dx = -1; dx <= 1; ++dx) {
            int nx = x + dx;
            if (nx < 0 || nx >= W) continue;
            int q = ny * W + nx;
            if (dmap[q] == (u8)(t - 1)) {
                cnt++;
                s0 += out[q];
                s1 += out[HW + q];
                s2 += out[2 * HW + q];
            }
        }
    }
    float inv = rcp_f((float)cnt + 1e-7f);
    int p = y * W + x;
    out[p]          = clamp01(s0 * inv);
    out[HW + p]     = clamp01(s1 * inv);
    out[2 * HW + p] = clamp01(s2 * inv);
}

__device__ __forceinline__ u32 has_byte2(u32 x) {
    u32 v = x ^ 0x02020202u;
    return (v - 0x01010101u) & ~v & 0x80808080u;
}

// t=2 pass: one thread gates on 16 dmap bytes (uint4).
__global__ __launch_bounds__(256) void tail_dense(
    float* __restrict__ out, const u8* __restrict__ dmap)
{
    int idx = blockIdx.x * 256 + threadIdx.x;
    int p = idx * 16;
    uint4 dq = *reinterpret_cast<const uint4*>(dmap + p);
    if (!(has_byte2(dq.x) | has_byte2(dq.y) | has_byte2(dq.z) | has_byte2(dq.w)))
        return;
    int y = p >> 12;            // p / W
    int xb = p & (W - 1);
    u32 words[4] = {dq.x, dq.y, dq.z, dq.w};
    #pragma unroll
    for (int wi = 0; wi < 4; ++wi) {
        u32 v = words[wi];
        #pragma unroll
        for (int b = 0; b < 4; ++b) {
            if (((v >> (8 * b)) & 0xFFu) == 2u)
                fill_pixel(out, dmap, xb + wi * 4 + b, y, 2);
        }
    }
}

// t=3..16 in ONE single-block kernel over the compacted d>=3 list
// (expected ~0-2 entries).
__global__ __launch_bounds__(256) void tail_far(
    float* __restrict__ out, const u8* __restrict__ dmap,
    const int* __restrict__ list, const u32* __restrict__ cnt, u32 cap)
{
    u32 n = *cnt;
    if (n > cap) n = cap;
    for (int t = 3; t <= 16; ++t) {
        for (u32 i = threadIdx.x; i < n; i += 256) {
            int p = list[i];
            if (dmap[p] == (u8)t)
                fill_pixel(out, dmap, p & (W - 1), p >> 12, t);
        }
        __syncthreads();
    }
}

extern "C" void kernel_launch(void* const* d_in, const int* in_sizes, int n_in,
                              void* d_out, int out_size, void* d_ws, size_t ws_size,
                              hipStream_t stream) {
    const float* rgb   = (const float*)d_in[0];
    const float* alpha = (const float*)d_in[1];
    float* out = (float*)d_out;

    u8* dmap  = (u8*)d_ws;                           // HW bytes
    u32* cnt  = (u32*)((char*)d_ws + HW);            // 4 bytes (16B slot)
    int* list = (int*)((char*)d_ws + HW + 16);
    u32 cap = 0;
    if (ws_size > (size_t)HW + 16) {
        size_t c = (ws_size - HW - 16) / 4;
        cap = (u32)(c > (1u << 22) ? (1u << 22) : c);
    }

    hipMemsetAsync(cnt, 0, 4, stream);

    pass1_kernel<<<dim3(GRID_X, GRID_Y), dim3(BX, BY), 0, stream>>>(
        rgb, alpha, out, dmap, cnt, list, cap);
    tail_dense<<<HW / 16 / 256, 256, 0, stream>>>(out, dmap);
    tail_far<<<1, 256, 0, stream>>>(out, dmap, list, cnt, cap);
}